// Round 15
// baseline (167.558 us; speedup 1.0000x reference)
//
#include <hip/hip_runtime.h>
#include <math.h>

// Problem: b=2, h=8, n=1024, d=64, DIM=512. Inputs/outputs FLOAT32.
// Internal pipeline bf16 MFMA (f32 accumulate). SCALE = 1/8.
// R15 = R14 + two fractional-occupancy fixes:
//  - k_qk retiled 128x128/1152blk -> 64x128/2304blk; +256 vct = 2560 = 10x256
//    (every CU-group: 9 uniform qk units + 1 vct; was 5-vs-4 full tiles)
//  - k_prep x-part 1024 -> 576 grid-stride blocks; total 1024 = 4x256 exact

typedef __bf16 bf16x8 __attribute__((ext_vector_type(8)));
typedef float f32x4 __attribute__((ext_vector_type(4)));

#define SCALE 0.125f

// async global->LDS: lane deposits 16B at (wave-uniform base + lane*16)
#define GLL(g, l) __builtin_amdgcn_global_load_lds(                         \
    (const __attribute__((address_space(1))) void*)(g),                     \
    (__attribute__((address_space(3))) void*)(l), 16, 0, 0)

__device__ __forceinline__ unsigned short f2bf(float f){
  unsigned int x = __builtin_bit_cast(unsigned int, f);
  unsigned int r = (x + 0x7fffu + ((x >> 16) & 1u)) >> 16;  // RNE
  return (unsigned short)r;
}
__device__ __forceinline__ float bf2f(unsigned short u){
  unsigned int x = ((unsigned int)u) << 16;
  return __builtin_bit_cast(float, x);
}
__device__ __forceinline__ f32x4 mfma16(bf16x8 a, bf16x8 b, f32x4 c){
  return __builtin_amdgcn_mfma_f32_16x16x32_bf16(a, b, c, 0, 0, 0);
}
__device__ __forceinline__ bf16x8 ld8(const unsigned short* p){
  return *(const bf16x8*)p;
}

// balanced tile permutation for k_scores (R13, max-slot already optimal at 9)
__device__ const unsigned char SC_TI[36] =
  {2,3,1,3, 7,6,7,5, 6,7,4,5, 6,7,5,7,
   0,2,2,4, 6,7,5,6, 7,4,5,6, 3,4,6,7,
   1,3,4,5};
__device__ const unsigned char SC_TJ[36] =
  {0,1,0,2, 0,0,1,0, 1,2,0,1, 2,3,2,4,
   0,2,1,3, 6,7,4,5, 6,2,3,4, 0,1,3,5,
   1,3,4,5};

// cumulative tile counts for 64-row-band lower-tri: CUM[rb] = sum ceil((r+1)/2)
__device__ const unsigned char QK_CUM[16] =
  {0,1,2,4,6,9,12,16,20,25,30,36,42,49,56,64};   // total 72

// ---------------- K0: x f32->bf16 (blocks 0..575, stride) + w transpose -----
__global__ __launch_bounds__(256) void k_prep(
    const float* __restrict__ x,
    const float* __restrict__ w0, const float* __restrict__ w1,
    const float* __restrict__ w2, const float* __restrict__ w3,
    const float* __restrict__ w4, const float* __restrict__ w5,
    const float* __restrict__ w6,
    unsigned short* __restrict__ xb, unsigned short* __restrict__ wT){
  int t = threadIdx.x;
  if (blockIdx.x < 576){
    for (int i = blockIdx.x * 256 + t; i < 262144; i += 576 * 256){
      float4 v = ((const float4*)x)[i];
      ushort4 o; o.x = f2bf(v.x); o.y = f2bf(v.y); o.z = f2bf(v.z); o.w = f2bf(v.w);
      ((ushort4*)xb)[i] = o;
    }
    return;
  }
  __shared__ float lds[64 * 65];
  int bx = blockIdx.x - 576;                    // 448 = 7 mats * 64 tiles
  int mat = bx >> 6, tile = bx & 63, tr = tile >> 3, tc = tile & 7;
  int k0 = tr * 64, c0 = tc * 64;
  const float* src;
  switch (mat){
    case 0: src = w0; break; case 1: src = w1; break; case 2: src = w2; break;
    case 3: src = w3; break; case 4: src = w4; break; case 5: src = w5; break;
    default: src = w6; break;
  }
#pragma unroll
  for (int i = 0; i < 4; ++i){
    int r = (t >> 4) + i * 16, c4 = (t & 15) * 4;
    float4 v = *(const float4*)(src + (size_t)(k0 + r) * 512 + c0 + c4);
    lds[r * 65 + c4 + 0] = v.x; lds[r * 65 + c4 + 1] = v.y;
    lds[r * 65 + c4 + 2] = v.z; lds[r * 65 + c4 + 3] = v.w;
  }
  __syncthreads();
  unsigned short* dst = wT + (size_t)mat * 262144;
#pragma unroll
  for (int i = 0; i < 4; ++i){
    int oc = (t >> 4) + i * 16;
    int kq = (t & 15) * 4;
    ushort4 o;
    o.x = f2bf(lds[(kq + 0) * 65 + oc]);
    o.y = f2bf(lds[(kq + 1) * 65 + oc]);
    o.z = f2bf(lds[(kq + 2) * 65 + oc]);
    o.w = f2bf(lds[(kq + 3) * 65 + oc]);
    *(ushort4*)(dst + (size_t)(c0 + oc) * 512 + k0 + kq) = o;
  }
}

// ---------------- K1: fused projections, 64x128 tiles, 768 blocks -----------
__global__ __launch_bounds__(256) void k_proj(
    const unsigned short* __restrict__ xb, const unsigned short* __restrict__ wT,
    unsigned short* __restrict__ P){
  __shared__ unsigned short sA[64 * 32], sB[128 * 32];
  int t = threadIdx.x, lane = t & 63, l16 = lane & 15, quad = lane >> 4;
  int w = t >> 6, wm = w >> 1, wn = w & 1;
  int bx = blockIdx.x;                       // 768 = 32 Mtiles * 24 Ntiles
  int mt = bx / 24, nt = bx - mt * 24;
  int M0 = mt * 64, N0 = nt * 128;
  int matb = N0 >> 9;
  int nin = N0 & 511;
  int srow = (lane >> 2), scol = (lane & 3) * 8;
  const unsigned short* gA = xb + (size_t)(M0 + w*16 + srow) * 512 + scol;
  const unsigned short* gB = wT + (size_t)matb * 262144
                               + (size_t)(nin + w*32 + srow) * 512 + scol;
  unsigned short* lA = sA + (w*16) * 32;
  unsigned short* lB = sB + (w*32) * 32;
  f32x4 acc[4][2] = {};
  for (int k0 = 0; k0 < 512; k0 += 32){
    GLL(gA + k0,            lA);
    GLL(gB + k0,            lB);
    GLL(gB + k0 + 16*512,   lB + 16*32);
    __syncthreads();
    bf16x8 aw[4], ax[2];
#pragma unroll
    for (int fi = 0; fi < 4; ++fi)
      aw[fi] = *(const bf16x8*)(sB + (wn*64 + fi*16 + l16) * 32 + quad * 8);
#pragma unroll
    for (int mi = 0; mi < 2; ++mi)
      ax[mi] = *(const bf16x8*)(sA + (wm*32 + mi*16 + l16) * 32 + quad * 8);
#pragma unroll
    for (int fi = 0; fi < 4; ++fi)
#pragma unroll
      for (int mi = 0; mi < 2; ++mi)
        acc[fi][mi] = mfma16(aw[fi], ax[mi], acc[fi][mi]);
    __syncthreads();
  }
#pragma unroll
  for (int fi = 0; fi < 4; ++fi)
#pragma unroll
    for (int mi = 0; mi < 2; ++mi){
      int row = M0 + wm*32 + mi*16 + l16;
      int b_ = row >> 10, n_ = row & 1023;
      int c0 = N0 + wn*64 + fi*16 + quad*4;
      int h = (c0 & 511) >> 6, d = c0 & 63;
      int bh = b_*8 + h;
      ushort4 o;
      o.x = f2bf(acc[fi][mi][0]); o.y = f2bf(acc[fi][mi][1]);
      o.z = f2bf(acc[fi][mi][2]); o.w = f2bf(acc[fi][mi][3]);
      *(ushort4*)(P + (size_t)(matb*16 + bh) * 65536 + (size_t)n_ * 64 + d) = o;
    }
}

// ---------------- K2: vct (blocks 0..255) + qk as 64x128 GLL-staged tiles ---
// 2304 qk blocks (16 bh x (72 term1 + 72 sig)); grid 2560 = 10x256 exact.
__global__ __launch_bounds__(256) void k_qk_vct(
    const unsigned short* __restrict__ P,
    unsigned short* __restrict__ term1, unsigned short* __restrict__ sig,
    unsigned short* __restrict__ vcT){
  int t = threadIdx.x;
  if (blockIdx.x < 256){
    __shared__ unsigned short lds[64 * 72];
    int bh = blockIdx.x >> 4, nt = blockIdx.x & 15;
    int N0 = nt * 64;
    const unsigned short* src = P + (size_t)(5*16 + bh) * 65536 + (size_t)N0 * 64;
#pragma unroll
    for (int i2 = 0; i2 < 2; ++i2){
      int id = i2 * 256 + t;
      int r = id >> 3, c8 = (id & 7) * 8;
      ushort4 v0 = *(const ushort4*)(src + r * 64 + c8);
      ushort4 v1 = *(const ushort4*)(src + r * 64 + c8 + 4);
      *(ushort4*)(lds + r * 72 + c8) = v0;
      *(ushort4*)(lds + r * 72 + c8 + 4) = v1;
    }
    __syncthreads();
    unsigned short* dst = vcT + (size_t)bh * 65536;
#pragma unroll
    for (int i2 = 0; i2 < 2; ++i2){
      int id = i2 * 256 + t;
      int dd = id >> 3, n8 = (id & 7) * 8;
      ushort4 a, b;
      a.x = lds[(n8+0)*72 + dd]; a.y = lds[(n8+1)*72 + dd];
      a.z = lds[(n8+2)*72 + dd]; a.w = lds[(n8+3)*72 + dd];
      b.x = lds[(n8+4)*72 + dd]; b.y = lds[(n8+5)*72 + dd];
      b.z = lds[(n8+6)*72 + dd]; b.w = lds[(n8+7)*72 + dd];
      *(ushort4*)(dst + (size_t)dd * 1024 + N0 + n8) = a;
      *(ushort4*)(dst + (size_t)dd * 1024 + N0 + n8 + 4) = b;
    }
    return;
  }
  __shared__ unsigned short sA[64 * 32], sB[128 * 32];
  int id = blockIdx.x - 256;
  int bh = id & 15, tt = id >> 4;              // tt in [0,144)
  int mat = (tt >= 72);                        // 0=term1, 1=sig
  int tl = mat ? tt - 72 : tt;                 // [0,72)
  int rb = 15;
  while (QK_CUM[rb] > tl) --rb;
  int ct = tl - QK_CUM[rb];                    // ct <= rb>>1
  int R0, C0;
  const unsigned short *Asrc, *Bsrc;
  if (!mat){ R0 = rb * 64;        C0 = ct * 128;        // term1 rows=i, cols=j
             Asrc = P + (size_t)(3*16 + bh) * 65536;    // q_c
             Bsrc = P + (size_t)(2*16 + bh) * 65536; }  // v_u
  else     { R0 = (15 - rb) * 64; C0 = (7 - ct) * 128;  // sig rows=k, cols=j
             Asrc = P + (size_t)(0*16 + bh) * 65536;    // q_u
             Bsrc = P + (size_t)(1*16 + bh) * 65536; }  // k_u
  int lane = t & 63, l16 = lane & 15, quad = lane >> 4;
  int w = t >> 6, wm = w >> 1, wn = w & 1;
  int srow = lane >> 2, scol = (lane & 3) * 8;
  const unsigned short* gA = Asrc + (size_t)(R0 + w*16 + srow) * 64 + scol;
  const unsigned short* gB = Bsrc + (size_t)(C0 + w*32 + srow) * 64 + scol;
  unsigned short* lA = sA + (w*16) * 32;
  unsigned short* lB = sB + (w*32) * 32;
  f32x4 acc[4][2] = {};                        // [fi=col grp][mi=row grp]
#pragma unroll
  for (int k0 = 0; k0 < 64; k0 += 32){
    GLL(gA + k0,           lA);
    GLL(gB + k0,           lB);
    GLL(gB + k0 + 16*64,   lB + 16*32);
    __syncthreads();
    bf16x8 af[2], bfr[4];
#pragma unroll
    for (int mi = 0; mi < 2; ++mi)
      af[mi] = *(const bf16x8*)(sA + (wm*32 + mi*16 + l16) * 32 + quad * 8);
#pragma unroll
    for (int fi = 0; fi < 4; ++fi)
      bfr[fi] = *(const bf16x8*)(sB + (wn*64 + fi*16 + l16) * 32 + quad * 8);
#pragma unroll
    for (int fi = 0; fi < 4; ++fi)
#pragma unroll
      for (int mi = 0; mi < 2; ++mi)
        acc[fi][mi] = mfma16(bfr[fi], af[mi], acc[fi][mi]);
    __syncthreads();
  }
  unsigned short* out = (mat ? sig : term1) + (size_t)bh * 1048576;
#pragma unroll
  for (int fi = 0; fi < 4; ++fi)
#pragma unroll
    for (int mi = 0; mi < 2; ++mi){
      int row = R0 + wm*32 + mi*16 + l16;
      int c0 = C0 + wn*64 + fi*16 + quad*4;
      ushort4 o;
#pragma unroll
      for (int r = 0; r < 4; ++r){
        int col = c0 + r;
        float v = acc[fi][mi][r] * SCALE;
        unsigned short res;
        if (!mat) res = (col <= row) ? f2bf(v) : (unsigned short)0;
        else      res = (col >  row) ? f2bf(1.f / (1.f + expf(-v))) : (unsigned short)0;
        ((unsigned short*)&o)[r] = res;
      }
      *(ushort4*)(out + (size_t)row * 1024 + c0) = o;
    }
}

// ---------------- K3: finb(bf16) = S_c - silu(S_u), lower tiles only --------
__global__ __launch_bounds__(256) void k_scores(
    const unsigned short* __restrict__ P, const unsigned short* __restrict__ term1,
    const unsigned short* __restrict__ sig, unsigned short* __restrict__ finb){
  __shared__ unsigned short sA[128 * 32], sB[128 * 32];
  int t = threadIdx.x;
  int bh = blockIdx.x & 15, tt = blockIdx.x >> 4;
  int ti = SC_TI[tt], tj = SC_TJ[tt];
  int delta = ti - tj;
  int M0 = ti * 128, N0 = tj * 128;
  size_t sbase = (size_t)bh * 1048576;
  int lane = t & 63, l16 = lane & 15, quad = lane >> 4;
  int w = t >> 6, wm = w >> 1, wn = w & 1;
  int srow = (lane >> 2), scol = (lane & 3) * 8;
  unsigned short* lA = sA + (w*32) * 32;
  unsigned short* lB = sB + (w*32) * 32;
  f32x4 acc_u[4][4] = {};
  f32x4 acc_c[4][4] = {};
  {
    const unsigned short* gA = term1 + sbase + (size_t)(M0 + w*32 + srow) * 1024 + scol;
    const unsigned short* gB = sig   + sbase + (size_t)(N0 + w*32 + srow) * 1024 + scol;
    int steps = (delta + 1) * 4;
    for (int s = 0; s < steps; ++s){
      int j0 = N0 + s * 32;
      GLL(gA + j0,             lA);
      GLL(gA + j0 + 16*1024,   lA + 16*32);
      GLL(gB + j0,             lB);
      GLL(gB + j0 + 16*1024,   lB + 16*32);
      __syncthreads();
      bf16x8 af[4], bfr[4];
#pragma unroll
      for (int mi = 0; mi < 4; ++mi)
        af[mi] = *(const bf16x8*)(sA + (wm*64 + mi*16 + l16) * 32 + quad * 8);
#pragma unroll
      for (int fi = 0; fi < 4; ++fi)
        bfr[fi] = *(const bf16x8*)(sB + (wn*64 + fi*16 + l16) * 32 + quad * 8);
#pragma unroll
      for (int fi = 0; fi < 4; ++fi)
#pragma unroll
        for (int mi = 0; mi < 4; ++mi)
          acc_u[fi][mi] = mfma16(bfr[fi], af[mi], acc_u[fi][mi]);
      __syncthreads();
    }
  }
  {
    const unsigned short* Qc = P + (size_t)(3*16 + bh) * 65536;
    const unsigned short* Kc = P + (size_t)(4*16 + bh) * 65536;
#pragma unroll
    for (int k0 = 0; k0 < 64; k0 += 32){
      bf16x8 af[4], bfr[4];
#pragma unroll
      for (int mi = 0; mi < 4; ++mi)
        af[mi] = ld8(Qc + (size_t)(M0 + wm*64 + mi*16 + l16) * 64 + k0 + quad * 8);
#pragma unroll
      for (int fi = 0; fi < 4; ++fi)
        bfr[fi] = ld8(Kc + (size_t)(N0 + wn*64 + fi*16 + l16) * 64 + k0 + quad * 8);
#pragma unroll
      for (int fi = 0; fi < 4; ++fi)
#pragma unroll
        for (int mi = 0; mi < 4; ++mi)
          acc_c[fi][mi] = mfma16(bfr[fi], af[mi], acc_c[fi][mi]);
    }
  }
  unsigned short* out = finb + sbase;
#pragma unroll
  for (int fi = 0; fi < 4; ++fi)
#pragma unroll
    for (int mi = 0; mi < 4; ++mi){
      int row = M0 + wm*64 + mi*16 + l16;
      int c0 = N0 + wn*64 + fi*16 + quad*4;
      ushort4 o;
#pragma unroll
      for (int r = 0; r < 4; ++r){
        float su = acc_u[fi][mi][r];
        float v = acc_c[fi][mi][r] * SCALE - su / (1.f + expf(-su));
        ((unsigned short*)&o)[r] = f2bf(v);   // col>row masked downstream
      }
      *(ushort4*)(out + (size_t)row * 1024 + c0) = o;
    }
}

// ---------------- K4: fused softmax + PV; snake mt map; O2 [2048][512] ------
__global__ __launch_bounds__(256) void k_pv_soft(
    const unsigned short* __restrict__ finb, const unsigned short* __restrict__ vcT,
    unsigned short* __restrict__ O2){
  __shared__ __align__(16) unsigned char smem[16 * 1032 * 2];  // 33 KB
  unsigned short* lp = (unsigned short*)smem;                  // probs [16][1032]
  float* red = (float*)smem;                                   // overlay
  int t = threadIdx.x;
  int bh = blockIdx.x & 15;
  int r4 = blockIdx.x >> 8, g = (blockIdx.x >> 4) & 15;
  // snake: CU-group g gets mts {63-g, 32+g, 31-g, g} -> work-sum 126 const
  int mt = (r4 == 0) ? 63 - g : (r4 == 1) ? 32 + g : (r4 == 2) ? 31 - g : g;
  int m0 = mt * 16;
  int kceil = ((m0 + 16 + 31) >> 5) << 5;                      // mult of 32
  {
    int rl = t >> 4, sub = t & 15;
    int rloc = m0 + rl;
    const unsigned short* p = finb + (size_t)bh * 1048576 + (size_t)rloc * 1024;
    float v[8][8];
    float m = -INFINITY;
#pragma unroll
    for (int i = 0; i < 8; ++i){
      int c8 = (sub + 16*i) * 8;
      if (c8 < kceil){
        ushort4 u0 = *(const ushort4*)(p + c8);
        ushort4 u1 = *(const ushort4*)(p + c8 + 4);
        float vv[8] = {bf2f(u0.x), bf2f(u0.y), bf2f(u0.z), bf2f(u0.w),
                       bf2f(u1.x), bf2f(u1.y), bf2f(u1.z), bf2f(u1.w)};
#pragma unroll
        for (int e = 0; e < 8; ++e){
          v[i][e] = (c8 + e <= rloc) ? vv[e] : -INFINITY;
          m = fmaxf(m, v[i][e]);
        }
      }
    }
#pragma unroll
    for (int off = 1; off < 16; off <<= 1) m = fmaxf(m, __shfl_xor(m, off));
    float s = 0.f;
#pragma unroll
    for (int i = 0; i < 8; ++i){
      int c8 = (sub + 16*i) * 8;
      if (c8 < kceil){
#pragma unroll
        for (int e = 0; e < 8; ++e){
          v[i][e] = expf(v[i][e] - m);
          s += v[i][e];
        }
      }
    }
#pragma unroll
    for (int off = 1; off < 16; off <<= 1) s += __shfl_xor(s, off);
    float inv = 1.f / s;
#pragma unroll
    for (int i = 0; i < 8; ++i){
      int c8 = (sub + 16*i) * 8;
      if (c8 < kceil){
        ushort4 o0, o1;
        o0.x = f2bf(v[i][0] * inv); o0.y = f2bf(v[i][1] * inv);
        o0.z = f2bf(v[i][2] * inv); o0.w = f2bf(v[i][3] * inv);
        o1.x = f2bf(v[i][4] * inv); o1.y = f2bf(v[i][5] * inv);
        o1.z = f2bf(v[i][6] * inv); o1.w = f2bf(v[i][7] * inv);
        *(ushort4*)(lp + rl * 1032 + c8) = o0;
        *(ushort4*)(lp + rl * 1032 + c8 + 4) = o1;
      }
    }
  }
  __syncthreads();
  int lane = t & 63, l16 = lane & 15, quad = lane >> 4, w = t >> 6;
  const unsigned short* Bt = vcT + (size_t)bh * 65536;
  int ktot = kceil >> 5;
  int per = (ktot + 3) >> 2;
  int s0 = w * per, s1 = min(s0 + per, ktot);
  f32x4 acc[4] = {};
  for (int s = s0; s < s1; ++s){
    int k0 = s * 32;
    bf16x8 a = *(const bf16x8*)(lp + l16 * 1032 + k0 + quad * 8);
#pragma unroll
    for (int fi = 0; fi < 4; ++fi){
      bf16x8 b = ld8(Bt + (size_t)(fi*16 + l16) * 1024 + k0 + quad * 8);
      acc[fi] = mfma16(a, b, acc[fi]);
    }
  }
  __syncthreads();
#pragma unroll
  for (int fi = 0; fi < 4; ++fi)
#pragma unroll
    for (int r = 0; r < 4; ++r)
      red[w * 1024 + (quad*4 + r) * 64 + fi*16 + l16] = acc[fi][r];
  __syncthreads();
  float4 a0 = ((const float4*)(red + 0*1024))[t];
  float4 a1 = ((const float4*)(red + 1*1024))[t];
  float4 a2 = ((const float4*)(red + 2*1024))[t];
  float4 a3 = ((const float4*)(red + 3*1024))[t];
  ushort4 o;
  o.x = f2bf(a0.x + a1.x + a2.x + a3.x);
  o.y = f2bf(a0.y + a1.y + a2.y + a3.y);
  o.z = f2bf(a0.z + a1.z + a2.z + a3.z);
  o.w = f2bf(a0.w + a1.w + a2.w + a3.w);
  int e = t * 4, row = e >> 6, col = e & 63;
  int b_ = bh >> 3, h_ = bh & 7;
  *(ushort4*)(O2 + (size_t)(b_*1024 + m0 + row) * 512 + h_*64 + col) = o;
}

// ---------------- K5: out(f32) = O_cat @ w_out (contiguous A reads) ---------
__global__ __launch_bounds__(256) void k_out(
    const unsigned short* __restrict__ O2, const unsigned short* __restrict__ woT,
    float* __restrict__ out){
  __shared__ float red[4][1024];
  int t = threadIdx.x, lane = t & 63, l16 = lane & 15, quad = lane >> 4, w = t >> 6;
  int mt = blockIdx.x >> 3, nt = blockIdx.x & 7;
  int m0 = mt * 16, n0 = nt * 64;
  int r_ = m0 + l16;
  f32x4 acc[4] = {};
#pragma unroll
  for (int s = 0; s < 4; ++s){
    int kk = w * 128 + s * 32 + quad * 8;
    bf16x8 a = ld8(O2 + (size_t)r_ * 512 + kk);
#pragma unroll
    for (int fi = 0; fi < 4; ++fi){
      bf16x8 b = ld8(woT + (size_t)(n0 + fi*16 + l16) * 512 + kk);
      acc[fi] = mfma16(a, b, acc[fi]);
    }
  }
#pragma unroll
  for (int fi = 0; fi < 4; ++fi)
#pragma unroll
    for (int r = 0; r < 4; ++r)
      red[w][(quad*4 + r) * 64 + fi*16 + l16] = acc[fi][r];
  __syncthreads();
  float4 a0 = ((const float4*)red[0])[t];
  float4 a1 = ((const float4*)red[1])[t];
  float4 a2 = ((const float4*)red[2])[t];
  float4 a3 = ((const float4*)red[3])[t];
  float4 o;
  o.x = a0.x + a1.x + a2.x + a3.x;
  o.y = a0.y + a1.y + a2.y + a3.y;
  o.z = a0.z + a1.z + a2.z + a3.z;
  o.w = a0.w + a1.w + a2.w + a3.w;
  int e = t * 4, row = e >> 6, col = e & 63;
  *(float4*)(out + (size_t)(m0 + row) * 512 + n0 + col) = o;
}

extern "C" void kernel_launch(void* const* d_in, const int* in_sizes, int n_in,
                              void* d_out, int out_size, void* d_ws, size_t ws_size,
                              hipStream_t stream){
  const float* x = (const float*)d_in[0];
  float* out = (float*)d_out;
  unsigned short* ws = (unsigned short*)d_ws;

  unsigned short* wT    = ws;                                   // 7*262144
  unsigned short* xb    = wT    + (size_t)7  * 262144;          // 1048576
  unsigned short* P     = xb    + (size_t)1048576;              // 96*65536
  unsigned short* vcT   = P     + (size_t)96 * 65536;           // 16*65536
  unsigned short* term1 = vcT   + (size_t)16 * 65536;           // 16*1048576
  unsigned short* sig   = term1 + (size_t)16 * 1048576;         // 16*1048576
  unsigned short* O2    = sig   + (size_t)16 * 1048576;         // 16*65536 ([2048][512])
  unsigned short* finb  = O2    + (size_t)16 * 65536;           // 16*1048576 bf16

  k_prep<<<1024, 256, 0, stream>>>(
      x,
      (const float*)d_in[1], (const float*)d_in[2], (const float*)d_in[3],
      (const float*)d_in[4], (const float*)d_in[5], (const float*)d_in[6],
      (const float*)d_in[7], xb, wT);
  k_proj<<<768, 256, 0, stream>>>(xb, wT, P);
  k_qk_vct<<<2560, 256, 0, stream>>>(P, term1, sig, vcT);
  k_scores<<<576, 256, 0, stream>>>(P, term1, sig, finb);
  k_pv_soft<<<1024, 256, 0, stream>>>(finb, vcT, O2);
  k_out<<<1024, 256, 0, stream>>>(O2, wT + (size_t)6 * 262144, out);
}

// Round 16
// 163.269 us; speedup vs baseline: 1.0263x; 1.0263x over previous
//
#include <hip/hip_runtime.h>
#include <math.h>

// Problem: b=2, h=8, n=1024, d=64, DIM=512. Inputs/outputs FLOAT32.
// Internal pipeline bf16 MFMA (f32 accumulate). SCALE = 1/8.
// R16 = R15 + k_scores retiled 128x128/576blk -> 64x128/1152blk with a
// hand-balanced 72-slot tile permutation (CU-group step-sums 54..56).
// R15 profile: k_scores was 46us at 16% occupancy (2.25 blk/CU) — grid-bound.

typedef __bf16 bf16x8 __attribute__((ext_vector_type(8)));
typedef float f32x4 __attribute__((ext_vector_type(4)));

#define SCALE 0.125f

// async global->LDS: lane deposits 16B at (wave-uniform base + lane*16)
#define GLL(g, l) __builtin_amdgcn_global_load_lds(                         \
    (const __attribute__((address_space(1))) void*)(g),                     \
    (__attribute__((address_space(3))) void*)(l), 16, 0, 0)

__device__ __forceinline__ unsigned short f2bf(float f){
  unsigned int x = __builtin_bit_cast(unsigned int, f);
  unsigned int r = (x + 0x7fffu + ((x >> 16) & 1u)) >> 16;  // RNE
  return (unsigned short)r;
}
__device__ __forceinline__ float bf2f(unsigned short u){
  unsigned int x = ((unsigned int)u) << 16;
  return __builtin_bit_cast(float, x);
}
__device__ __forceinline__ f32x4 mfma16(bf16x8 a, bf16x8 b, f32x4 c){
  return __builtin_amdgcn_mfma_f32_16x16x32_bf16(a, b, c, 0, 0, 0);
}
__device__ __forceinline__ bf16x8 ld8(const unsigned short* p){
  return *(const bf16x8*)p;
}

// cumulative tile counts for 64-row-band lower-tri (k_qk map)
__device__ const unsigned char QK_CUM[16] =
  {0,1,2,4,6,9,12,16,20,25,30,36,42,49,56,64};   // total 72

// k_scores 64x128-band tile permutation: slot tt -> (rb, ct), rb=row band
// (64 rows), ct=col tile (128 cols), ct <= rb>>1. Greedy-LPT balanced:
// CU-group g=tt%16 step-sums 54..56 (naive layout: 2..32 per tile).
__device__ const unsigned char SC_RB[72] =
  {15,14,11,13,15,10,12,14,15,14,13,12,15,13,11, 9,
   12, 8, 6,15,13,11, 9, 7,15,13,14,10,14,12,10, 8,
    9, 3,14,12,10, 8, 6, 4,15,13,11, 7,11, 9, 7, 5,
   13,10, 8,11, 9, 6, 4, 2,15,14,12, 5, 7, 5, 3, 1,
   14,12,10, 8, 6, 4, 2, 0};
__device__ const unsigned char SC_CT[72] =
  { 1, 1, 0, 1, 2, 0, 1, 2, 0, 0, 0, 0, 3, 2, 1, 0,
    3, 1, 0, 4, 3, 2, 1, 0, 5, 4, 4, 2, 3, 2, 1, 0,
    3, 0, 5, 4, 3, 2, 1, 0, 6, 5, 4, 2, 3, 2, 1, 0,
    6, 4, 3, 5, 4, 2, 1, 0, 7, 6, 5, 1, 3, 2, 1, 0,
    7, 6, 5, 4, 3, 2, 1, 0};

// ---------------- K0: x f32->bf16 (blocks 0..575, stride) + w transpose -----
__global__ __launch_bounds__(256) void k_prep(
    const float* __restrict__ x,
    const float* __restrict__ w0, const float* __restrict__ w1,
    const float* __restrict__ w2, const float* __restrict__ w3,
    const float* __restrict__ w4, const float* __restrict__ w5,
    const float* __restrict__ w6,
    unsigned short* __restrict__ xb, unsigned short* __restrict__ wT){
  int t = threadIdx.x;
  if (blockIdx.x < 576){
    for (int i = blockIdx.x * 256 + t; i < 262144; i += 576 * 256){
      float4 v = ((const float4*)x)[i];
      ushort4 o; o.x = f2bf(v.x); o.y = f2bf(v.y); o.z = f2bf(v.z); o.w = f2bf(v.w);
      ((ushort4*)xb)[i] = o;
    }
    return;
  }
  __shared__ float lds[64 * 65];
  int bx = blockIdx.x - 576;                    // 448 = 7 mats * 64 tiles
  int mat = bx >> 6, tile = bx & 63, tr = tile >> 3, tc = tile & 7;
  int k0 = tr * 64, c0 = tc * 64;
  const float* src;
  switch (mat){
    case 0: src = w0; break; case 1: src = w1; break; case 2: src = w2; break;
    case 3: src = w3; break; case 4: src = w4; break; case 5: src = w5; break;
    default: src = w6; break;
  }
#pragma unroll
  for (int i = 0; i < 4; ++i){
    int r = (t >> 4) + i * 16, c4 = (t & 15) * 4;
    float4 v = *(const float4*)(src + (size_t)(k0 + r) * 512 + c0 + c4);
    lds[r * 65 + c4 + 0] = v.x; lds[r * 65 + c4 + 1] = v.y;
    lds[r * 65 + c4 + 2] = v.z; lds[r * 65 + c4 + 3] = v.w;
  }
  __syncthreads();
  unsigned short* dst = wT + (size_t)mat * 262144;
#pragma unroll
  for (int i = 0; i < 4; ++i){
    int oc = (t >> 4) + i * 16;
    int kq = (t & 15) * 4;
    ushort4 o;
    o.x = f2bf(lds[(kq + 0) * 65 + oc]);
    o.y = f2bf(lds[(kq + 1) * 65 + oc]);
    o.z = f2bf(lds[(kq + 2) * 65 + oc]);
    o.w = f2bf(lds[(kq + 3) * 65 + oc]);
    *(ushort4*)(dst + (size_t)(c0 + oc) * 512 + k0 + kq) = o;
  }
}

// ---------------- K1: fused projections, 64x128 tiles, 768 blocks -----------
__global__ __launch_bounds__(256) void k_proj(
    const unsigned short* __restrict__ xb, const unsigned short* __restrict__ wT,
    unsigned short* __restrict__ P){
  __shared__ unsigned short sA[64 * 32], sB[128 * 32];
  int t = threadIdx.x, lane = t & 63, l16 = lane & 15, quad = lane >> 4;
  int w = t >> 6, wm = w >> 1, wn = w & 1;
  int bx = blockIdx.x;                       // 768 = 32 Mtiles * 24 Ntiles
  int mt = bx / 24, nt = bx - mt * 24;
  int M0 = mt * 64, N0 = nt * 128;
  int matb = N0 >> 9;
  int nin = N0 & 511;
  int srow = (lane >> 2), scol = (lane & 3) * 8;
  const unsigned short* gA = xb + (size_t)(M0 + w*16 + srow) * 512 + scol;
  const unsigned short* gB = wT + (size_t)matb * 262144
                               + (size_t)(nin + w*32 + srow) * 512 + scol;
  unsigned short* lA = sA + (w*16) * 32;
  unsigned short* lB = sB + (w*32) * 32;
  f32x4 acc[4][2] = {};
  for (int k0 = 0; k0 < 512; k0 += 32){
    GLL(gA + k0,            lA);
    GLL(gB + k0,            lB);
    GLL(gB + k0 + 16*512,   lB + 16*32);
    __syncthreads();
    bf16x8 aw[4], ax[2];
#pragma unroll
    for (int fi = 0; fi < 4; ++fi)
      aw[fi] = *(const bf16x8*)(sB + (wn*64 + fi*16 + l16) * 32 + quad * 8);
#pragma unroll
    for (int mi = 0; mi < 2; ++mi)
      ax[mi] = *(const bf16x8*)(sA + (wm*32 + mi*16 + l16) * 32 + quad * 8);
#pragma unroll
    for (int fi = 0; fi < 4; ++fi)
#pragma unroll
      for (int mi = 0; mi < 2; ++mi)
        acc[fi][mi] = mfma16(aw[fi], ax[mi], acc[fi][mi]);
    __syncthreads();
  }
#pragma unroll
  for (int fi = 0; fi < 4; ++fi)
#pragma unroll
    for (int mi = 0; mi < 2; ++mi){
      int row = M0 + wm*32 + mi*16 + l16;
      int b_ = row >> 10, n_ = row & 1023;
      int c0 = N0 + wn*64 + fi*16 + quad*4;
      int h = (c0 & 511) >> 6, d = c0 & 63;
      int bh = b_*8 + h;
      ushort4 o;
      o.x = f2bf(acc[fi][mi][0]); o.y = f2bf(acc[fi][mi][1]);
      o.z = f2bf(acc[fi][mi][2]); o.w = f2bf(acc[fi][mi][3]);
      *(ushort4*)(P + (size_t)(matb*16 + bh) * 65536 + (size_t)n_ * 64 + d) = o;
    }
}

// ---------------- K2: vct (blocks 0..255) + qk as 64x128 GLL-staged tiles ---
__global__ __launch_bounds__(256) void k_qk_vct(
    const unsigned short* __restrict__ P,
    unsigned short* __restrict__ term1, unsigned short* __restrict__ sig,
    unsigned short* __restrict__ vcT){
  int t = threadIdx.x;
  if (blockIdx.x < 256){
    __shared__ unsigned short lds[64 * 72];
    int bh = blockIdx.x >> 4, nt = blockIdx.x & 15;
    int N0 = nt * 64;
    const unsigned short* src = P + (size_t)(5*16 + bh) * 65536 + (size_t)N0 * 64;
#pragma unroll
    for (int i2 = 0; i2 < 2; ++i2){
      int id = i2 * 256 + t;
      int r = id >> 3, c8 = (id & 7) * 8;
      ushort4 v0 = *(const ushort4*)(src + r * 64 + c8);
      ushort4 v1 = *(const ushort4*)(src + r * 64 + c8 + 4);
      *(ushort4*)(lds + r * 72 + c8) = v0;
      *(ushort4*)(lds + r * 72 + c8 + 4) = v1;
    }
    __syncthreads();
    unsigned short* dst = vcT + (size_t)bh * 65536;
#pragma unroll
    for (int i2 = 0; i2 < 2; ++i2){
      int id = i2 * 256 + t;
      int dd = id >> 3, n8 = (id & 7) * 8;
      ushort4 a, b;
      a.x = lds[(n8+0)*72 + dd]; a.y = lds[(n8+1)*72 + dd];
      a.z = lds[(n8+2)*72 + dd]; a.w = lds[(n8+3)*72 + dd];
      b.x = lds[(n8+4)*72 + dd]; b.y = lds[(n8+5)*72 + dd];
      b.z = lds[(n8+6)*72 + dd]; b.w = lds[(n8+7)*72 + dd];
      *(ushort4*)(dst + (size_t)dd * 1024 + N0 + n8) = a;
      *(ushort4*)(dst + (size_t)dd * 1024 + N0 + n8 + 4) = b;
    }
    return;
  }
  __shared__ unsigned short sA[64 * 32], sB[128 * 32];
  int id = blockIdx.x - 256;
  int bh = id & 15, tt = id >> 4;              // tt in [0,144)
  int mat = (tt >= 72);                        // 0=term1, 1=sig
  int tl = mat ? tt - 72 : tt;                 // [0,72)
  int rb = 15;
  while (QK_CUM[rb] > tl) --rb;
  int ct = tl - QK_CUM[rb];                    // ct <= rb>>1
  int R0, C0;
  const unsigned short *Asrc, *Bsrc;
  if (!mat){ R0 = rb * 64;        C0 = ct * 128;        // term1 rows=i, cols=j
             Asrc = P + (size_t)(3*16 + bh) * 65536;    // q_c
             Bsrc = P + (size_t)(2*16 + bh) * 65536; }  // v_u
  else     { R0 = (15 - rb) * 64; C0 = (7 - ct) * 128;  // sig rows=k, cols=j
             Asrc = P + (size_t)(0*16 + bh) * 65536;    // q_u
             Bsrc = P + (size_t)(1*16 + bh) * 65536; }  // k_u
  int lane = t & 63, l16 = lane & 15, quad = lane >> 4;
  int w = t >> 6, wm = w >> 1, wn = w & 1;
  int srow = lane >> 2, scol = (lane & 3) * 8;
  const unsigned short* gA = Asrc + (size_t)(R0 + w*16 + srow) * 64 + scol;
  const unsigned short* gB = Bsrc + (size_t)(C0 + w*32 + srow) * 64 + scol;
  unsigned short* lA = sA + (w*16) * 32;
  unsigned short* lB = sB + (w*32) * 32;
  f32x4 acc[4][2] = {};
#pragma unroll
  for (int k0 = 0; k0 < 64; k0 += 32){
    GLL(gA + k0,           lA);
    GLL(gB + k0,           lB);
    GLL(gB + k0 + 16*64,   lB + 16*32);
    __syncthreads();
    bf16x8 af[2], bfr[4];
#pragma unroll
    for (int mi = 0; mi < 2; ++mi)
      af[mi] = *(const bf16x8*)(sA + (wm*32 + mi*16 + l16) * 32 + quad * 8);
#pragma unroll
    for (int fi = 0; fi < 4; ++fi)
      bfr[fi] = *(const bf16x8*)(sB + (wn*64 + fi*16 + l16) * 32 + quad * 8);
#pragma unroll
    for (int fi = 0; fi < 4; ++fi)
#pragma unroll
      for (int mi = 0; mi < 2; ++mi)
        acc[fi][mi] = mfma16(bfr[fi], af[mi], acc[fi][mi]);
    __syncthreads();
  }
  unsigned short* out = (mat ? sig : term1) + (size_t)bh * 1048576;
#pragma unroll
  for (int fi = 0; fi < 4; ++fi)
#pragma unroll
    for (int mi = 0; mi < 2; ++mi){
      int row = R0 + wm*32 + mi*16 + l16;
      int c0 = C0 + wn*64 + fi*16 + quad*4;
      ushort4 o;
#pragma unroll
      for (int r = 0; r < 4; ++r){
        int col = c0 + r;
        float v = acc[fi][mi][r] * SCALE;
        unsigned short res;
        if (!mat) res = (col <= row) ? f2bf(v) : (unsigned short)0;
        else      res = (col >  row) ? f2bf(1.f / (1.f + expf(-v))) : (unsigned short)0;
        ((unsigned short*)&o)[r] = res;
      }
      *(ushort4*)(out + (size_t)row * 1024 + c0) = o;
    }
}

// ---------------- K3: finb(bf16) = S_c - silu(S_u), 64x128 bands ------------
// 1152 blocks = 72 balanced slots x 16 bh; 4.5 blocks/CU.
__global__ __launch_bounds__(256) void k_scores(
    const unsigned short* __restrict__ P, const unsigned short* __restrict__ term1,
    const unsigned short* __restrict__ sig, unsigned short* __restrict__ finb){
  __shared__ unsigned short sA[64 * 32], sB[128 * 32];
  int t = threadIdx.x;
  int bh = blockIdx.x & 15, tt = blockIdx.x >> 4;   // tt in [0,72)
  int rb = SC_RB[tt], ct = SC_CT[tt];
  int R0 = rb * 64, C0 = ct * 128;
  size_t sbase = (size_t)bh * 1048576;
  int lane = t & 63, l16 = lane & 15, quad = lane >> 4;
  int w = t >> 6, wm = w >> 1, wn = w & 1;
  int srow = lane >> 2, scol = (lane & 3) * 8;
  unsigned short* lA = sA + (w*16) * 32;
  unsigned short* lB = sB + (w*32) * 32;
  f32x4 acc_u[4][2] = {};                   // [fi=col grp (k)][mi=row grp (i)]
  f32x4 acc_c[4][2] = {};
  {
    const unsigned short* gA = term1 + sbase + (size_t)(R0 + w*16 + srow) * 1024 + scol;
    const unsigned short* gB = sig   + sbase + (size_t)(C0 + w*32 + srow) * 1024 + scol;
    int steps = (R0 + 64 - C0) >> 5;        // j in [C0, R0+64), 32-chunks
    for (int s = 0; s < steps; ++s){
      int j0 = C0 + s * 32;
      GLL(gA + j0,           lA);
      GLL(gB + j0,           lB);
      GLL(gB + j0 + 16*1024, lB + 16*32);
      __syncthreads();
      bf16x8 af[2], bfr[4];
#pragma unroll
      for (int mi = 0; mi < 2; ++mi)
        af[mi] = *(const bf16x8*)(sA + (wm*32 + mi*16 + l16) * 32 + quad * 8);
#pragma unroll
      for (int fi = 0; fi < 4; ++fi)
        bfr[fi] = *(const bf16x8*)(sB + (wn*64 + fi*16 + l16) * 32 + quad * 8);
#pragma unroll
      for (int fi = 0; fi < 4; ++fi)
#pragma unroll
        for (int mi = 0; mi < 2; ++mi)
          acc_u[fi][mi] = mfma16(bfr[fi], af[mi], acc_u[fi][mi]);
      __syncthreads();
    }
  }
  {
    const unsigned short* Qc = P + (size_t)(3*16 + bh) * 65536;
    const unsigned short* Kc = P + (size_t)(4*16 + bh) * 65536;
#pragma unroll
    for (int k0 = 0; k0 < 64; k0 += 32){
      bf16x8 af[2], bfr[4];
#pragma unroll
      for (int mi = 0; mi < 2; ++mi)
        af[mi] = ld8(Qc + (size_t)(R0 + wm*32 + mi*16 + l16) * 64 + k0 + quad * 8);
#pragma unroll
      for (int fi = 0; fi < 4; ++fi)
        bfr[fi] = ld8(Kc + (size_t)(C0 + wn*64 + fi*16 + l16) * 64 + k0 + quad * 8);
#pragma unroll
      for (int fi = 0; fi < 4; ++fi)
#pragma unroll
        for (int mi = 0; mi < 2; ++mi)
          acc_c[fi][mi] = mfma16(bfr[fi], af[mi], acc_c[fi][mi]);
    }
  }
  unsigned short* out = finb + sbase;
#pragma unroll
  for (int fi = 0; fi < 4; ++fi)
#pragma unroll
    for (int mi = 0; mi < 2; ++mi){
      int row = R0 + wm*32 + mi*16 + l16;
      int c0 = C0 + wn*64 + fi*16 + quad*4;
      ushort4 o;
#pragma unroll
      for (int r = 0; r < 4; ++r){
        float su = acc_u[fi][mi][r];
        float v = acc_c[fi][mi][r] * SCALE - su / (1.f + expf(-su));
        ((unsigned short*)&o)[r] = f2bf(v);   // col>row masked downstream
      }
      *(ushort4*)(out + (size_t)row * 1024 + c0) = o;
    }
}

// ---------------- K4: fused softmax + PV; snake mt map; O2 [2048][512] ------
__global__ __launch_bounds__(256) void k_pv_soft(
    const unsigned short* __restrict__ finb, const unsigned short* __restrict__ vcT,
    unsigned short* __restrict__ O2){
  __shared__ __align__(16) unsigned char smem[16 * 1032 * 2];  // 33 KB
  unsigned short* lp = (unsigned short*)smem;                  // probs [16][1032]
  float* red = (float*)smem;                                   // overlay
  int t = threadIdx.x;
  int bh = blockIdx.x & 15;
  int r4 = blockIdx.x >> 8, g = (blockIdx.x >> 4) & 15;
  // snake: CU-group g gets mts {63-g, 32+g, 31-g, g} -> work-sum 126 const
  int mt = (r4 == 0) ? 63 - g : (r4 == 1) ? 32 + g : (r4 == 2) ? 31 - g : g;
  int m0 = mt * 16;
  int kceil = ((m0 + 16 + 31) >> 5) << 5;                      // mult of 32
  {
    int rl = t >> 4, sub = t & 15;
    int rloc = m0 + rl;
    const unsigned short* p = finb + (size_t)bh * 1048576 + (size_t)rloc * 1024;
    float v[8][8];
    float m = -INFINITY;
#pragma unroll
    for (int i = 0; i < 8; ++i){
      int c8 = (sub + 16*i) * 8;
      if (c8 < kceil){
        ushort4 u0 = *(const ushort4*)(p + c8);
        ushort4 u1 = *(const ushort4*)(p + c8 + 4);
        float vv[8] = {bf2f(u0.x), bf2f(u0.y), bf2f(u0.z), bf2f(u0.w),
                       bf2f(u1.x), bf2f(u1.y), bf2f(u1.z), bf2f(u1.w)};
#pragma unroll
        for (int e = 0; e < 8; ++e){
          v[i][e] = (c8 + e <= rloc) ? vv[e] : -INFINITY;
          m = fmaxf(m, v[i][e]);
        }
      }
    }
#pragma unroll
    for (int off = 1; off < 16; off <<= 1) m = fmaxf(m, __shfl_xor(m, off));
    float s = 0.f;
#pragma unroll
    for (int i = 0; i < 8; ++i){
      int c8 = (sub + 16*i) * 8;
      if (c8 < kceil){
#pragma unroll
        for (int e = 0; e < 8; ++e){
          v[i][e] = expf(v[i][e] - m);
          s += v[i][e];
        }
      }
    }
#pragma unroll
    for (int off = 1; off < 16; off <<= 1) s += __shfl_xor(s, off);
    float inv = 1.f / s;
#pragma unroll
    for (int i = 0; i < 8; ++i){
      int c8 = (sub + 16*i) * 8;
      if (c8 < kceil){
        ushort4 o0, o1;
        o0.x = f2bf(v[i][0] * inv); o0.y = f2bf(v[i][1] * inv);
        o0.z = f2bf(v[i][2] * inv); o0.w = f2bf(v[i][3] * inv);
        o1.x = f2bf(v[i][4] * inv); o1.y = f2bf(v[i][5] * inv);
        o1.z = f2bf(v[i][6] * inv); o1.w = f2bf(v[i][7] * inv);
        *(ushort4*)(lp + rl * 1032 + c8) = o0;
        *(ushort4*)(lp + rl * 1032 + c8 + 4) = o1;
      }
    }
  }
  __syncthreads();
  int lane = t & 63, l16 = lane & 15, quad = lane >> 4, w = t >> 6;
  const unsigned short* Bt = vcT + (size_t)bh * 65536;
  int ktot = kceil >> 5;
  int per = (ktot + 3) >> 2;
  int s0 = w * per, s1 = min(s0 + per, ktot);
  f32x4 acc[4] = {};
  for (int s = s0; s < s1; ++s){
    int k0 = s * 32;
    bf16x8 a = *(const bf16x8*)(lp + l16 * 1032 + k0 + quad * 8);
#pragma unroll
    for (int fi = 0; fi < 4; ++fi){
      bf16x8 b = ld8(Bt + (size_t)(fi*16 + l16) * 1024 + k0 + quad * 8);
      acc[fi] = mfma16(a, b, acc[fi]);
    }
  }
  __syncthreads();
#pragma unroll
  for (int fi = 0; fi < 4; ++fi)
#pragma unroll
    for (int r = 0; r < 4; ++r)
      red[w * 1024 + (quad*4 + r) * 64 + fi*16 + l16] = acc[fi][r];
  __syncthreads();
  float4 a0 = ((const float4*)(red + 0*1024))[t];
  float4 a1 = ((const float4*)(red + 1*1024))[t];
  float4 a2 = ((const float4*)(red + 2*1024))[t];
  float4 a3 = ((const float4*)(red + 3*1024))[t];
  ushort4 o;
  o.x = f2bf(a0.x + a1.x + a2.x + a3.x);
  o.y = f2bf(a0.y + a1.y + a2.y + a3.y);
  o.z = f2bf(a0.z + a1.z + a2.z + a3.z);
  o.w = f2bf(a0.w + a1.w + a2.w + a3.w);
  int e = t * 4, row = e >> 6, col = e & 63;
  int b_ = bh >> 3, h_ = bh & 7;
  *(ushort4*)(O2 + (size_t)(b_*1024 + m0 + row) * 512 + h_*64 + col) = o;
}

// ---------------- K5: out(f32) = O_cat @ w_out (contiguous A reads) ---------
__global__ __launch_bounds__(256) void k_out(
    const unsigned short* __restrict__ O2, const unsigned short* __restrict__ woT,
    float* __restrict__ out){
  __shared__ float red[4][1024];
  int t = threadIdx.x, lane = t & 63, l16 = lane & 15, quad = lane >> 4, w = t >> 6;
  int mt = blockIdx.x >> 3, nt = blockIdx.x & 7;
  int m0 = mt * 16, n0 = nt * 64;
  int r_ = m0 + l16;
  f32x4 acc[4] = {};
#pragma unroll
  for (int s = 0; s < 4; ++s){
    int kk = w * 128 + s * 32 + quad * 8;
    bf16x8 a = ld8(O2 + (size_t)r_ * 512 + kk);
#pragma unroll
    for (int fi = 0; fi < 4; ++fi){
      bf16x8 b = ld8(woT + (size_t)(n0 + fi*16 + l16) * 512 + kk);
      acc[fi] = mfma16(a, b, acc[fi]);
    }
  }
#pragma unroll
  for (int fi = 0; fi < 4; ++fi)
#pragma unroll
    for (int r = 0; r < 4; ++r)
      red[w][(quad*4 + r) * 64 + fi*16 + l16] = acc[fi][r];
  __syncthreads();
  float4 a0 = ((const float4*)red[0])[t];
  float4 a1 = ((const float4*)red[1])[t];
  float4 a2 = ((const float4*)red[2])[t];
  float4 a3 = ((const float4*)red[3])[t];
  float4 o;
  o.x = a0.x + a1.x + a2.x + a3.x;
  o.y = a0.y + a1.y + a2.y + a3.y;
  o.z = a0.z + a1.z + a2.z + a3.z;
  o.w = a0.w + a1.w + a2.w + a3.w;
  int e = t * 4, row = e >> 6, col = e & 63;
  *(float4*)(out + (size_t)(m0 + row) * 512 + n0 + col) = o;
}

extern "C" void kernel_launch(void* const* d_in, const int* in_sizes, int n_in,
                              void* d_out, int out_size, void* d_ws, size_t ws_size,
                              hipStream_t stream){
  const float* x = (const float*)d_in[0];
  float* out = (float*)d_out;
  unsigned short* ws = (unsigned short*)d_ws;

  unsigned short* wT    = ws;                                   // 7*262144
  unsigned short* xb    = wT    + (size_t)7  * 262144;          // 1048576
  unsigned short* P     = xb    + (size_t)1048576;              // 96*65536
  unsigned short* vcT   = P     + (size_t)96 * 65536;           // 16*65536
  unsigned short* term1 = vcT   + (size_t)16 * 65536;           // 16*1048576
  unsigned short* sig   = term1 + (size_t)16 * 1048576;         // 16*1048576
  unsigned short* O2    = sig   + (size_t)16 * 1048576;         // 16*65536 ([2048][512])
  unsigned short* finb  = O2    + (size_t)16 * 65536;           // 16*1048576 bf16

  k_prep<<<1024, 256, 0, stream>>>(
      x,
      (const float*)d_in[1], (const float*)d_in[2], (const float*)d_in[3],
      (const float*)d_in[4], (const float*)d_in[5], (const float*)d_in[6],
      (const float*)d_in[7], xb, wT);
  k_proj<<<768, 256, 0, stream>>>(xb, wT, P);
  k_qk_vct<<<2560, 256, 0, stream>>>(P, term1, sig, vcT);
  k_scores<<<1152, 256, 0, stream>>>(P, term1, sig, finb);
  k_pv_soft<<<1024, 256, 0, stream>>>(finb, vcT, O2);
  k_out<<<1024, 256, 0, stream>>>(O2, wT + (size_t)6 * 262144, out);
}

// Round 17
// 160.744 us; speedup vs baseline: 1.0424x; 1.0157x over previous
//
#include <hip/hip_runtime.h>
#include <math.h>

// Problem: b=2, h=8, n=1024, d=64, DIM=512. Inputs/outputs FLOAT32.
// Internal pipeline bf16 MFMA (f32 accumulate). SCALE = 1/8.
// R17 = R16 + BK=64 double-chunk staging in k_proj / k_qk_vct / k_scores:
// two 32-wide K-chunks land in split LDS halves per ONE barrier round
// (6 GLL -> sync -> 16 MFMA -> sync), halving barrier/drain count while
// keeping the proven conflict-free 32-elem-row LDS layout (GLL needs
// unpadded contiguous deposits).

typedef __bf16 bf16x8 __attribute__((ext_vector_type(8)));
typedef float f32x4 __attribute__((ext_vector_type(4)));

#define SCALE 0.125f

// async global->LDS: lane deposits 16B at (wave-uniform base + lane*16)
#define GLL(g, l) __builtin_amdgcn_global_load_lds(                         \
    (const __attribute__((address_space(1))) void*)(g),                     \
    (__attribute__((address_space(3))) void*)(l), 16, 0, 0)

__device__ __forceinline__ unsigned short f2bf(float f){
  unsigned int x = __builtin_bit_cast(unsigned int, f);
  unsigned int r = (x + 0x7fffu + ((x >> 16) & 1u)) >> 16;  // RNE
  return (unsigned short)r;
}
__device__ __forceinline__ float bf2f(unsigned short u){
  unsigned int x = ((unsigned int)u) << 16;
  return __builtin_bit_cast(float, x);
}
__device__ __forceinline__ f32x4 mfma16(bf16x8 a, bf16x8 b, f32x4 c){
  return __builtin_amdgcn_mfma_f32_16x16x32_bf16(a, b, c, 0, 0, 0);
}
__device__ __forceinline__ bf16x8 ld8(const unsigned short* p){
  return *(const bf16x8*)p;
}

// cumulative tile counts for 64-row-band lower-tri (k_qk map)
__device__ const unsigned char QK_CUM[16] =
  {0,1,2,4,6,9,12,16,20,25,30,36,42,49,56,64};   // total 72

// k_scores 64x128-band tile permutation (R16, CU-group step-sums 54..56)
__device__ const unsigned char SC_RB[72] =
  {15,14,11,13,15,10,12,14,15,14,13,12,15,13,11, 9,
   12, 8, 6,15,13,11, 9, 7,15,13,14,10,14,12,10, 8,
    9, 3,14,12,10, 8, 6, 4,15,13,11, 7,11, 9, 7, 5,
   13,10, 8,11, 9, 6, 4, 2,15,14,12, 5, 7, 5, 3, 1,
   14,12,10, 8, 6, 4, 2, 0};
__device__ const unsigned char SC_CT[72] =
  { 1, 1, 0, 1, 2, 0, 1, 2, 0, 0, 0, 0, 3, 2, 1, 0,
    3, 1, 0, 4, 3, 2, 1, 0, 5, 4, 4, 2, 3, 2, 1, 0,
    3, 0, 5, 4, 3, 2, 1, 0, 6, 5, 4, 2, 3, 2, 1, 0,
    6, 4, 3, 5, 4, 2, 1, 0, 7, 6, 5, 1, 3, 2, 1, 0,
    7, 6, 5, 4, 3, 2, 1, 0};

// ---------------- K0: x f32->bf16 (blocks 0..575, stride) + w transpose -----
__global__ __launch_bounds__(256) void k_prep(
    const float* __restrict__ x,
    const float* __restrict__ w0, const float* __restrict__ w1,
    const float* __restrict__ w2, const float* __restrict__ w3,
    const float* __restrict__ w4, const float* __restrict__ w5,
    const float* __restrict__ w6,
    unsigned short* __restrict__ xb, unsigned short* __restrict__ wT){
  int t = threadIdx.x;
  if (blockIdx.x < 576){
    for (int i = blockIdx.x * 256 + t; i < 262144; i += 576 * 256){
      float4 v = ((const float4*)x)[i];
      ushort4 o; o.x = f2bf(v.x); o.y = f2bf(v.y); o.z = f2bf(v.z); o.w = f2bf(v.w);
      ((ushort4*)xb)[i] = o;
    }
    return;
  }
  __shared__ float lds[64 * 65];
  int bx = blockIdx.x - 576;                    // 448 = 7 mats * 64 tiles
  int mat = bx >> 6, tile = bx & 63, tr = tile >> 3, tc = tile & 7;
  int k0 = tr * 64, c0 = tc * 64;
  const float* src;
  switch (mat){
    case 0: src = w0; break; case 1: src = w1; break; case 2: src = w2; break;
    case 3: src = w3; break; case 4: src = w4; break; case 5: src = w5; break;
    default: src = w6; break;
  }
#pragma unroll
  for (int i = 0; i < 4; ++i){
    int r = (t >> 4) + i * 16, c4 = (t & 15) * 4;
    float4 v = *(const float4*)(src + (size_t)(k0 + r) * 512 + c0 + c4);
    lds[r * 65 + c4 + 0] = v.x; lds[r * 65 + c4 + 1] = v.y;
    lds[r * 65 + c4 + 2] = v.z; lds[r * 65 + c4 + 3] = v.w;
  }
  __syncthreads();
  unsigned short* dst = wT + (size_t)mat * 262144;
#pragma unroll
  for (int i = 0; i < 4; ++i){
    int oc = (t >> 4) + i * 16;
    int kq = (t & 15) * 4;
    ushort4 o;
    o.x = f2bf(lds[(kq + 0) * 65 + oc]);
    o.y = f2bf(lds[(kq + 1) * 65 + oc]);
    o.z = f2bf(lds[(kq + 2) * 65 + oc]);
    o.w = f2bf(lds[(kq + 3) * 65 + oc]);
    *(ushort4*)(dst + (size_t)(c0 + oc) * 512 + k0 + kq) = o;
  }
}

// ---------------- K1: fused projections, 64x128 tiles, 768 blocks -----------
// BK=64: two 32-chunks per barrier round (8 rounds over K=512).
__global__ __launch_bounds__(256) void k_proj(
    const unsigned short* __restrict__ xb, const unsigned short* __restrict__ wT,
    unsigned short* __restrict__ P){
  __shared__ unsigned short sA[2 * 64 * 32], sB[2 * 128 * 32];
  int t = threadIdx.x, lane = t & 63, l16 = lane & 15, quad = lane >> 4;
  int w = t >> 6, wm = w >> 1, wn = w & 1;
  int bx = blockIdx.x;                       // 768 = 32 Mtiles * 24 Ntiles
  int mt = bx / 24, nt = bx - mt * 24;
  int M0 = mt * 64, N0 = nt * 128;
  int matb = N0 >> 9;
  int nin = N0 & 511;
  int srow = (lane >> 2), scol = (lane & 3) * 8;
  const unsigned short* gA = xb + (size_t)(M0 + w*16 + srow) * 512 + scol;
  const unsigned short* gB = wT + (size_t)matb * 262144
                               + (size_t)(nin + w*32 + srow) * 512 + scol;
  unsigned short* lA0 = sA + (w*16) * 32;
  unsigned short* lB0 = sB + (w*32) * 32;
  unsigned short* lA1 = lA0 + 64 * 32;
  unsigned short* lB1 = lB0 + 128 * 32;
  f32x4 acc[4][2] = {};
  for (int k0 = 0; k0 < 512; k0 += 64){
    GLL(gA + k0,               lA0);
    GLL(gB + k0,               lB0);
    GLL(gB + k0 + 16*512,      lB0 + 16*32);
    GLL(gA + k0 + 32,          lA1);
    GLL(gB + k0 + 32,          lB1);
    GLL(gB + k0 + 32 + 16*512, lB1 + 16*32);
    __syncthreads();
#pragma unroll
    for (int h = 0; h < 2; ++h){
      bf16x8 aw[4], ax[2];
#pragma unroll
      for (int fi = 0; fi < 4; ++fi)
        aw[fi] = *(const bf16x8*)(sB + h*4096 + (wn*64 + fi*16 + l16) * 32 + quad * 8);
#pragma unroll
      for (int mi = 0; mi < 2; ++mi)
        ax[mi] = *(const bf16x8*)(sA + h*2048 + (wm*32 + mi*16 + l16) * 32 + quad * 8);
#pragma unroll
      for (int fi = 0; fi < 4; ++fi)
#pragma unroll
        for (int mi = 0; mi < 2; ++mi)
          acc[fi][mi] = mfma16(aw[fi], ax[mi], acc[fi][mi]);
    }
    __syncthreads();
  }
#pragma unroll
  for (int fi = 0; fi < 4; ++fi)
#pragma unroll
    for (int mi = 0; mi < 2; ++mi){
      int row = M0 + wm*32 + mi*16 + l16;
      int b_ = row >> 10, n_ = row & 1023;
      int c0 = N0 + wn*64 + fi*16 + quad*4;
      int h = (c0 & 511) >> 6, d = c0 & 63;
      int bh = b_*8 + h;
      ushort4 o;
      o.x = f2bf(acc[fi][mi][0]); o.y = f2bf(acc[fi][mi][1]);
      o.z = f2bf(acc[fi][mi][2]); o.w = f2bf(acc[fi][mi][3]);
      *(ushort4*)(P + (size_t)(matb*16 + bh) * 65536 + (size_t)n_ * 64 + d) = o;
    }
}

// ---------------- K2: vct (blocks 0..255) + qk as 64x128, ONE barrier -------
__global__ __launch_bounds__(256) void k_qk_vct(
    const unsigned short* __restrict__ P,
    unsigned short* __restrict__ term1, unsigned short* __restrict__ sig,
    unsigned short* __restrict__ vcT){
  int t = threadIdx.x;
  if (blockIdx.x < 256){
    __shared__ unsigned short lds[64 * 72];
    int bh = blockIdx.x >> 4, nt = blockIdx.x & 15;
    int N0 = nt * 64;
    const unsigned short* src = P + (size_t)(5*16 + bh) * 65536 + (size_t)N0 * 64;
#pragma unroll
    for (int i2 = 0; i2 < 2; ++i2){
      int id = i2 * 256 + t;
      int r = id >> 3, c8 = (id & 7) * 8;
      ushort4 v0 = *(const ushort4*)(src + r * 64 + c8);
      ushort4 v1 = *(const ushort4*)(src + r * 64 + c8 + 4);
      *(ushort4*)(lds + r * 72 + c8) = v0;
      *(ushort4*)(lds + r * 72 + c8 + 4) = v1;
    }
    __syncthreads();
    unsigned short* dst = vcT + (size_t)bh * 65536;
#pragma unroll
    for (int i2 = 0; i2 < 2; ++i2){
      int id = i2 * 256 + t;
      int dd = id >> 3, n8 = (id & 7) * 8;
      ushort4 a, b;
      a.x = lds[(n8+0)*72 + dd]; a.y = lds[(n8+1)*72 + dd];
      a.z = lds[(n8+2)*72 + dd]; a.w = lds[(n8+3)*72 + dd];
      b.x = lds[(n8+4)*72 + dd]; b.y = lds[(n8+5)*72 + dd];
      b.z = lds[(n8+6)*72 + dd]; b.w = lds[(n8+7)*72 + dd];
      *(ushort4*)(dst + (size_t)dd * 1024 + N0 + n8) = a;
      *(ushort4*)(dst + (size_t)dd * 1024 + N0 + n8 + 4) = b;
    }
    return;
  }
  __shared__ unsigned short sA[2 * 64 * 32], sB[2 * 128 * 32];
  int id = blockIdx.x - 256;
  int bh = id & 15, tt = id >> 4;              // tt in [0,144)
  int mat = (tt >= 72);                        // 0=term1, 1=sig
  int tl = mat ? tt - 72 : tt;                 // [0,72)
  int rb = 15;
  while (QK_CUM[rb] > tl) --rb;
  int ct = tl - QK_CUM[rb];                    // ct <= rb>>1
  int R0, C0;
  const unsigned short *Asrc, *Bsrc;
  if (!mat){ R0 = rb * 64;        C0 = ct * 128;        // term1 rows=i, cols=j
             Asrc = P + (size_t)(3*16 + bh) * 65536;    // q_c
             Bsrc = P + (size_t)(2*16 + bh) * 65536; }  // v_u
  else     { R0 = (15 - rb) * 64; C0 = (7 - ct) * 128;  // sig rows=k, cols=j
             Asrc = P + (size_t)(0*16 + bh) * 65536;    // q_u
             Bsrc = P + (size_t)(1*16 + bh) * 65536; }  // k_u
  int lane = t & 63, l16 = lane & 15, quad = lane >> 4;
  int w = t >> 6, wm = w >> 1, wn = w & 1;
  int srow = lane >> 2, scol = (lane & 3) * 8;
  const unsigned short* gA = Asrc + (size_t)(R0 + w*16 + srow) * 64 + scol;
  const unsigned short* gB = Bsrc + (size_t)(C0 + w*32 + srow) * 64 + scol;
  unsigned short* lA0 = sA + (w*16) * 32;
  unsigned short* lB0 = sB + (w*32) * 32;
  unsigned short* lA1 = lA0 + 64 * 32;
  unsigned short* lB1 = lB0 + 128 * 32;
  f32x4 acc[4][2] = {};
  GLL(gA,              lA0);
  GLL(gB,              lB0);
  GLL(gB + 16*64,      lB0 + 16*32);
  GLL(gA + 32,         lA1);
  GLL(gB + 32,         lB1);
  GLL(gB + 32 + 16*64, lB1 + 16*32);
  __syncthreads();
#pragma unroll
  for (int h = 0; h < 2; ++h){
    bf16x8 af[2], bfr[4];
#pragma unroll
    for (int mi = 0; mi < 2; ++mi)
      af[mi] = *(const bf16x8*)(sA + h*2048 + (wm*32 + mi*16 + l16) * 32 + quad * 8);
#pragma unroll
    for (int fi = 0; fi < 4; ++fi)
      bfr[fi] = *(const bf16x8*)(sB + h*4096 + (wn*64 + fi*16 + l16) * 32 + quad * 8);
#pragma unroll
    for (int fi = 0; fi < 4; ++fi)
#pragma unroll
      for (int mi = 0; mi < 2; ++mi)
        acc[fi][mi] = mfma16(bfr[fi], af[mi], acc[fi][mi]);
  }
  unsigned short* out = (mat ? sig : term1) + (size_t)bh * 1048576;
#pragma unroll
  for (int fi = 0; fi < 4; ++fi)
#pragma unroll
    for (int mi = 0; mi < 2; ++mi){
      int row = R0 + wm*32 + mi*16 + l16;
      int c0 = C0 + wn*64 + fi*16 + quad*4;
      ushort4 o;
#pragma unroll
      for (int r = 0; r < 4; ++r){
        int col = c0 + r;
        float v = acc[fi][mi][r] * SCALE;
        unsigned short res;
        if (!mat) res = (col <= row) ? f2bf(v) : (unsigned short)0;
        else      res = (col >  row) ? f2bf(1.f / (1.f + expf(-v))) : (unsigned short)0;
        ((unsigned short*)&o)[r] = res;
      }
      *(ushort4*)(out + (size_t)row * 1024 + c0) = o;
    }
}

// ---------------- K3: finb(bf16) = S_c - silu(S_u), 64x128 bands ------------
// 1152 blocks; BK=64 double-chunk staging (rounds halved, odd tail handled).
__global__ __launch_bounds__(256) void k_scores(
    const unsigned short* __restrict__ P, const unsigned short* __restrict__ term1,
    const unsigned short* __restrict__ sig, unsigned short* __restrict__ finb){
  __shared__ unsigned short sA[2 * 64 * 32], sB[2 * 128 * 32];
  int t = threadIdx.x;
  int bh = blockIdx.x & 15, tt = blockIdx.x >> 4;   // tt in [0,72)
  int rb = SC_RB[tt], ct = SC_CT[tt];
  int R0 = rb * 64, C0 = ct * 128;
  size_t sbase = (size_t)bh * 1048576;
  int lane = t & 63, l16 = lane & 15, quad = lane >> 4;
  int w = t >> 6, wm = w >> 1, wn = w & 1;
  int srow = lane >> 2, scol = (lane & 3) * 8;
  unsigned short* lA0 = sA + (w*16) * 32;
  unsigned short* lB0 = sB + (w*32) * 32;
  unsigned short* lA1 = lA0 + 64 * 32;
  unsigned short* lB1 = lB0 + 128 * 32;
  f32x4 acc_u[4][2] = {};                   // [fi=col grp (k)][mi=row grp (i)]
  f32x4 acc_c[4][2] = {};
  {
    const unsigned short* gA = term1 + sbase + (size_t)(R0 + w*16 + srow) * 1024 + scol;
    const unsigned short* gB = sig   + sbase + (size_t)(C0 + w*32 + srow) * 1024 + scol;
    int nsteps = (R0 + 64 - C0) >> 5;       // 32-chunks, j in [C0, R0+64)
    for (int s = 0; s < nsteps; s += 2){
      int j0 = C0 + s * 32;
      int two = (s + 1 < nsteps);           // block-uniform
      GLL(gA + j0,             lA0);
      GLL(gB + j0,             lB0);
      GLL(gB + j0 + 16*1024,   lB0 + 16*32);
      if (two){
        GLL(gA + j0 + 32,           lA1);
        GLL(gB + j0 + 32,           lB1);
        GLL(gB + j0 + 32 + 16*1024, lB1 + 16*32);
      }
      __syncthreads();
      for (int h = 0; h <= two; ++h){
        bf16x8 af[2], bfr[4];
#pragma unroll
        for (int mi = 0; mi < 2; ++mi)
          af[mi] = *(const bf16x8*)(sA + h*2048 + (wm*32 + mi*16 + l16) * 32 + quad * 8);
#pragma unroll
        for (int fi = 0; fi < 4; ++fi)
          bfr[fi] = *(const bf16x8*)(sB + h*4096 + (wn*64 + fi*16 + l16) * 32 + quad * 8);
#pragma unroll
        for (int fi = 0; fi < 4; ++fi)
#pragma unroll
          for (int mi = 0; mi < 2; ++mi)
            acc_u[fi][mi] = mfma16(bfr[fi], af[mi], acc_u[fi][mi]);
      }
      __syncthreads();
    }
  }
  {
    const unsigned short* Qc = P + (size_t)(3*16 + bh) * 65536;
    const unsigned short* Kc = P + (size_t)(4*16 + bh) * 65536;
#pragma unroll
    for (int k0 = 0; k0 < 64; k0 += 32){
      bf16x8 af[2], bfr[4];
#pragma unroll
      for (int mi = 0; mi < 2; ++mi)
        af[mi] = ld8(Qc + (size_t)(R0 + wm*32 + mi*16 + l16) * 64 + k0 + quad * 8);
#pragma unroll
      for (int fi = 0; fi < 4; ++fi)
        bfr[fi] = ld8(Kc + (size_t)(C0 + wn*64 + fi*16 + l16) * 64 + k0 + quad * 8);
#pragma unroll
      for (int fi = 0; fi < 4; ++fi)
#pragma unroll
        for (int mi = 0; mi < 2; ++mi)
          acc_c[fi][mi] = mfma16(bfr[fi], af[mi], acc_c[fi][mi]);
    }
  }
  unsigned short* out = finb + sbase;
#pragma unroll
  for (int fi = 0; fi < 4; ++fi)
#pragma unroll
    for (int mi = 0; mi < 2; ++mi){
      int row = R0 + wm*32 + mi*16 + l16;
      int c0 = C0 + wn*64 + fi*16 + quad*4;
      ushort4 o;
#pragma unroll
      for (int r = 0; r < 4; ++r){
        float su = acc_u[fi][mi][r];
        float v = acc_c[fi][mi][r] * SCALE - su / (1.f + expf(-su));
        ((unsigned short*)&o)[r] = f2bf(v);   // col>row masked downstream
      }
      *(ushort4*)(out + (size_t)row * 1024 + c0) = o;
    }
}

// ---------------- K4: fused softmax + PV; snake mt map; O2 [2048][512] ------
__global__ __launch_bounds__(256) void k_pv_soft(
    const unsigned short* __restrict__ finb, const unsigned short* __restrict__ vcT,
    unsigned short* __restrict__ O2){
  __shared__ __align__(16) unsigned char smem[16 * 1032 * 2];  // 33 KB
  unsigned short* lp = (unsigned short*)smem;                  // probs [16][1032]
  float* red = (float*)smem;                                   // overlay
  int t = threadIdx.x;
  int bh = blockIdx.x & 15;
  int r4 = blockIdx.x >> 8, g = (blockIdx.x >> 4) & 15;
  // snake: CU-group g gets mts {63-g, 32+g, 31-g, g} -> work-sum 126 const
  int mt = (r4 == 0) ? 63 - g : (r4 == 1) ? 32 + g : (r4 == 2) ? 31 - g : g;
  int m0 = mt * 16;
  int kceil = ((m0 + 16 + 31) >> 5) << 5;                      // mult of 32
  {
    int rl = t >> 4, sub = t & 15;
    int rloc = m0 + rl;
    const unsigned short* p = finb + (size_t)bh * 1048576 + (size_t)rloc * 1024;
    float v[8][8];
    float m = -INFINITY;
#pragma unroll
    for (int i = 0; i < 8; ++i){
      int c8 = (sub + 16*i) * 8;
      if (c8 < kceil){
        ushort4 u0 = *(const ushort4*)(p + c8);
        ushort4 u1 = *(const ushort4*)(p + c8 + 4);
        float vv[8] = {bf2f(u0.x), bf2f(u0.y), bf2f(u0.z), bf2f(u0.w),
                       bf2f(u1.x), bf2f(u1.y), bf2f(u1.z), bf2f(u1.w)};
#pragma unroll
        for (int e = 0; e < 8; ++e){
          v[i][e] = (c8 + e <= rloc) ? vv[e] : -INFINITY;
          m = fmaxf(m, v[i][e]);
        }
      }
    }
#pragma unroll
    for (int off = 1; off < 16; off <<= 1) m = fmaxf(m, __shfl_xor(m, off));
    float s = 0.f;
#pragma unroll
    for (int i = 0; i < 8; ++i){
      int c8 = (sub + 16*i) * 8;
      if (c8 < kceil){
#pragma unroll
        for (int e = 0; e < 8; ++e){
          v[i][e] = expf(v[i][e] - m);
          s += v[i][e];
        }
      }
    }
#pragma unroll
    for (int off = 1; off < 16; off <<= 1) s += __shfl_xor(s, off);
    float inv = 1.f / s;
#pragma unroll
    for (int i = 0; i < 8; ++i){
      int c8 = (sub + 16*i) * 8;
      if (c8 < kceil){
        ushort4 o0, o1;
        o0.x = f2bf(v[i][0] * inv); o0.y = f2bf(v[i][1] * inv);
        o0.z = f2bf(v[i][2] * inv); o0.w = f2bf(v[i][3] * inv);
        o1.x = f2bf(v[i][4] * inv); o1.y = f2bf(v[i][5] * inv);
        o1.z = f2bf(v[i][6] * inv); o1.w = f2bf(v[i][7] * inv);
        *(ushort4*)(lp + rl * 1032 + c8) = o0;
        *(ushort4*)(lp + rl * 1032 + c8 + 4) = o1;
      }
    }
  }
  __syncthreads();
  int lane = t & 63, l16 = lane & 15, quad = lane >> 4, w = t >> 6;
  const unsigned short* Bt = vcT + (size_t)bh * 65536;
  int ktot = kceil >> 5;
  int per = (ktot + 3) >> 2;
  int s0 = w * per, s1 = min(s0 + per, ktot);
  f32x4 acc[4] = {};
  for (int s = s0; s < s1; ++s){
    int k0 = s * 32;
    bf16x8 a = *(const bf16x8*)(lp + l16 * 1032 + k0 + quad * 8);
#pragma unroll
    for (int fi = 0; fi < 4; ++fi){
      bf16x8 b = ld8(Bt + (size_t)(fi*16 + l16) * 1024 + k0 + quad * 8);
      acc[fi] = mfma16(a, b, acc[fi]);
    }
  }
  __syncthreads();
#pragma unroll
  for (int fi = 0; fi < 4; ++fi)
#pragma unroll
    for (int r = 0; r < 4; ++r)
      red[w * 1024 + (quad*4 + r) * 64 + fi*16 + l16] = acc[fi][r];
  __syncthreads();
  float4 a0 = ((const float4*)(red + 0*1024))[t];
  float4 a1 = ((const float4*)(red + 1*1024))[t];
  float4 a2 = ((const float4*)(red + 2*1024))[t];
  float4 a3 = ((const float4*)(red + 3*1024))[t];
  ushort4 o;
  o.x = f2bf(a0.x + a1.x + a2.x + a3.x);
  o.y = f2bf(a0.y + a1.y + a2.y + a3.y);
  o.z = f2bf(a0.z + a1.z + a2.z + a3.z);
  o.w = f2bf(a0.w + a1.w + a2.w + a3.w);
  int e = t * 4, row = e >> 6, col = e & 63;
  int b_ = bh >> 3, h_ = bh & 7;
  *(ushort4*)(O2 + (size_t)(b_*1024 + m0 + row) * 512 + h_*64 + col) = o;
}

// ---------------- K5: out(f32) = O_cat @ w_out (contiguous A reads) ---------
__global__ __launch_bounds__(256) void k_out(
    const unsigned short* __restrict__ O2, const unsigned short* __restrict__ woT,
    float* __restrict__ out){
  __shared__ float red[4][1024];
  int t = threadIdx.x, lane = t & 63, l16 = lane & 15, quad = lane >> 4, w = t >> 6;
  int mt = blockIdx.x >> 3, nt = blockIdx.x & 7;
  int m0 = mt * 16, n0 = nt * 64;
  int r_ = m0 + l16;
  f32x4 acc[4] = {};
#pragma unroll
  for (int s = 0; s < 4; ++s){
    int kk = w * 128 + s * 32 + quad * 8;
    bf16x8 a = ld8(O2 + (size_t)r_ * 512 + kk);
#pragma unroll
    for (int fi = 0; fi < 4; ++fi){
      bf16x8 b = ld8(woT + (size_t)(n0 + fi*16 + l16) * 512 + kk);
      acc[fi] = mfma16(a, b, acc[fi]);
    }
  }
#pragma unroll
  for (int fi = 0; fi < 4; ++fi)
#pragma unroll
    for (int r = 0; r < 4; ++r)
      red[w][(quad*4 + r) * 64 + fi*16 + l16] = acc[fi][r];
  __syncthreads();
  float4 a0 = ((const float4*)red[0])[t];
  float4 a1 = ((const float4*)red[1])[t];
  float4 a2 = ((const float4*)red[2])[t];
  float4 a3 = ((const float4*)red[3])[t];
  float4 o;
  o.x = a0.x + a1.x + a2.x + a3.x;
  o.y = a0.y + a1.y + a2.y + a3.y;
  o.z = a0.z + a1.z + a2.z + a3.z;
  o.w = a0.w + a1.w + a2.w + a3.w;
  int e = t * 4, row = e >> 6, col = e & 63;
  *(float4*)(out + (size_t)(m0 + row) * 512 + n0 + col) = o;
}

extern "C" void kernel_launch(void* const* d_in, const int* in_sizes, int n_in,
                              void* d_out, int out_size, void* d_ws, size_t ws_size,
                              hipStream_t stream){
  const float* x = (const float*)d_in[0];
  float* out = (float*)d_out;
  unsigned short* ws = (unsigned short*)d_ws;

  unsigned short* wT    = ws;                                   // 7*262144
  unsigned short* xb    = wT    + (size_t)7  * 262144;          // 1048576
  unsigned short* P     = xb    + (size_t)1048576;              // 96*65536
  unsigned short* vcT   = P     + (size_t)96 * 65536;           // 16*65536
  unsigned short* term1 = vcT   + (size_t)16 * 65536;           // 16*1048576
  unsigned short* sig   = term1 + (size_t)16 * 1048576;         // 16*1048576
  unsigned short* O2    = sig   + (size_t)16 * 1048576;         // 16*65536 ([2048][512])
  unsigned short* finb  = O2    + (size_t)16 * 65536;           // 16*1048576 bf16

  k_prep<<<1024, 256, 0, stream>>>(
      x,
      (const float*)d_in[1], (const float*)d_in[2], (const float*)d_in[3],
      (const float*)d_in[4], (const float*)d_in[5], (const float*)d_in[6],
      (const float*)d_in[7], xb, wT);
  k_proj<<<768, 256, 0, stream>>>(xb, wT, P);
  k_qk_vct<<<2560, 256, 0, stream>>>(P, term1, sig, vcT);
  k_scores<<<1152, 256, 0, stream>>>(P, term1, sig, finb);
  k_pv_soft<<<1024, 256, 0, stream>>>(finb, vcT, O2);
  k_out<<<1024, 256, 0, stream>>>(O2, wT + (size_t)6 * 262144, out);
}